// Round 6
// baseline (256.680 us; speedup 1.0000x reference)
//
#include <hip/hip_runtime.h>

constexpr int kB  = 16;
constexpr int kLM = 1024;
constexpr int kLX = 1024;
constexpr int kD  = 768;

using short8 = __attribute__((ext_vector_type(8))) short;
using f32x4  = __attribute__((ext_vector_type(4))) float;

__device__ __forceinline__ unsigned short f2bf(float f) {
    unsigned u = __float_as_uint(f);
    u = (u + 0x7FFF + ((u >> 16) & 1)) >> 16;   // RNE
    return (unsigned short)u;
}
__device__ __forceinline__ float bf2f(unsigned short h) {
    return __uint_as_float(((unsigned)h) << 16);
}

// async 16B global->LDS copy; dst must be wave-uniform base + lane*16.
__device__ __forceinline__ void gl_lds16(const unsigned short* g, unsigned short* l) {
    auto gp = (const __attribute__((address_space(1))) unsigned int*)g;
    auto lp = (__attribute__((address_space(3))) unsigned int*)l;
    __builtin_amdgcn_global_load_lds(gp, lp, 16, 0, 0);
}

// cvt 8 fp32 -> one 16B bf16 chunk, guaranteed ds_write (as3 store)
__device__ __forceinline__ void writeChunkLDS(unsigned short* dst, float4 lo, float4 hi) {
    union { short8 v; unsigned short u[8]; } o;
    o.u[0] = f2bf(lo.x); o.u[1] = f2bf(lo.y); o.u[2] = f2bf(lo.z); o.u[3] = f2bf(lo.w);
    o.u[4] = f2bf(hi.x); o.u[5] = f2bf(hi.y); o.u[6] = f2bf(hi.z); o.u[7] = f2bf(hi.w);
    auto lp = (__attribute__((address_space(3))) short8*)dst;
    *lp = o.v;
}

// ---------------------------------------------------------------------------
// 128x128 NT bf16 MFMA GEMM core (R3-proven). BK=64 full-line rows, 256 thr
// (2x2 waves), 4x4 frags x 2 k-slices = 32 MFMA/K-step/wave.
// LDS per operand per buffer: 128 rows x 8 chunks of 16B, XOR-swizzled
// (slot p <-> global row=p>>3, ch=(p&7)^(row&7)); conflict-free (measured 0).
//
// AFP32=false (both operands bf16, R3 exact): dbuf, depth-2 DMA issue,
//   gate s_waitcnt vmcnt(8) (tile t+1's 8 loads stay in flight).
// AFP32=true (A = fp32, converted in-staging; B bf16 DMA):
//   prologue: ldA(0)+wrA(0), B0, ldA(1), B1   [compiler-barrier separated]
//   gate kt=0: vmcnt(12)+lgkm(0)  (waits B0; A1+B1=12 in flight)
//   gate kt>0: lgkm(0) only       (wrA's ds_writes visible before BAR1)
//   post-BAR2: vmcnt(0) [drains 1-iter-old ldA(kt+1),B(kt+1)] -> wrA(kt+1),
//              then issue B(kt+2), ldA(kt+2) (stay in flight a full iter).
// ---------------------------------------------------------------------------
template <bool AFP32>
__device__ __forceinline__ void gemm_core64(
    const void* __restrict__ Av, const unsigned short* __restrict__ Bb,
    unsigned short* __restrict__ Cb, unsigned short* __restrict__ Cm,
    int N, int K, unsigned short* As0, unsigned short* Bs0) {
    const unsigned short* Ah = AFP32 ? nullptr : (const unsigned short*)Av;
    const float*          Af = AFP32 ? (const float*)Av : nullptr;
    const int t    = threadIdx.x;
    const int wave = t >> 6, lane = t & 63;
    const int wr = (wave >> 1) * 64, wc = (wave & 1) * 64;
    const int quad = lane >> 4, l15 = lane & 15;

    size_t goff[4];
    int    lof[4];
#pragma unroll
    for (int m = 0; m < 4; ++m) {
        const int p   = t + 256 * m;
        const int row = p >> 3;
        const int ch  = (p & 7) ^ (row & 7);
        goff[m] = (size_t)row * K + ch * 8;
        lof[m]  = p * 8;
    }

    const int perm0 = quad ^ (l15 & 7);
    const int aOff  = (wr + l15) * 64 + perm0 * 8;
    const int bOff  = (wc + l15) * 64 + perm0 * 8;

    f32x4 acc[4][4];
    const f32x4 z = {0.f, 0.f, 0.f, 0.f};
#pragma unroll
    for (int i = 0; i < 4; ++i)
#pragma unroll
        for (int j = 0; j < 4; ++j) acc[i][j] = z;

    const int T = K >> 6;

    auto stageB = [&](int kt) {
        const size_t kk = (size_t)kt << 6;
        unsigned short* Bd = Bs0 + (kt & 1) * 8192;
#pragma unroll
        for (int m = 0; m < 4; ++m) gl_lds16(Bb + goff[m] + kk, Bd + lof[m]);
    };
    auto stageA = [&](int kt) {
        const size_t kk = (size_t)kt << 6;
        unsigned short* Ad = As0 + (kt & 1) * 8192;
#pragma unroll
        for (int m = 0; m < 4; ++m) gl_lds16(Ah + goff[m] + kk, Ad + lof[m]);
    };
    float4 pa[4][2];
    auto ldA = [&](int kt) {
        const size_t kk = (size_t)kt << 6;
#pragma unroll
        for (int m = 0; m < 4; ++m) {
            const float* s = Af + goff[m] + kk;
            pa[m][0] = *(const float4*)s;
            pa[m][1] = *(const float4*)(s + 4);
        }
    };
    auto wrA = [&](int kt) {
        unsigned short* Ad = As0 + (kt & 1) * 8192;
#pragma unroll
        for (int m = 0; m < 4; ++m) writeChunkLDS(Ad + lof[m], pa[m][0], pa[m][1]);
    };

    if constexpr (AFP32) {
        ldA(0); wrA(0);                           // drains own loads at use
        stageB(0);                                // B0: 4 vm
        asm volatile("" ::: "memory");            // pin issue order
        if (T > 1) {
            ldA(1);                               // A1: 8 vm
            asm volatile("" ::: "memory");
            stageB(1);                            // B1: 4 vm
        }
    } else {
        stageA(0); stageB(0);
        if (T > 1) { stageA(1); stageB(1); }
    }

    for (int kt = 0; kt < T; ++kt) {
        if constexpr (AFP32) {
            if (kt == 0) {
                if (T > 1) asm volatile("s_waitcnt vmcnt(12) lgkmcnt(0)" ::: "memory");
                else       asm volatile("s_waitcnt vmcnt(0) lgkmcnt(0)" ::: "memory");
            } else {
                asm volatile("s_waitcnt lgkmcnt(0)" ::: "memory");
            }
        } else {
            if (kt + 1 < T) asm volatile("s_waitcnt vmcnt(8)" ::: "memory");
            else            asm volatile("s_waitcnt vmcnt(0)" ::: "memory");
        }
        __builtin_amdgcn_s_barrier();             // BAR1: tile kt staged
        asm volatile("" ::: "memory");

        const unsigned short* aP = As0 + (kt & 1) * 8192;
        const unsigned short* bP = Bs0 + (kt & 1) * 8192;
        short8 a0[4], b0[4], a1[4], b1[4];
#pragma unroll
        for (int i = 0; i < 4; ++i) a0[i] = *(const short8*)(aP + aOff + i * 1024);
#pragma unroll
        for (int j = 0; j < 4; ++j) b0[j] = *(const short8*)(bP + bOff + j * 1024);
        __builtin_amdgcn_s_setprio(1);
#pragma unroll
        for (int i = 0; i < 4; ++i)
#pragma unroll
            for (int j = 0; j < 4; ++j)
                acc[i][j] = __builtin_amdgcn_mfma_f32_16x16x32_bf16(
                    a0[i], b0[j], acc[i][j], 0, 0, 0);
        __builtin_amdgcn_s_setprio(0);
#pragma unroll
        for (int i = 0; i < 4; ++i) a1[i] = *(const short8*)(aP + (aOff ^ 32) + i * 1024);
#pragma unroll
        for (int j = 0; j < 4; ++j) b1[j] = *(const short8*)(bP + (bOff ^ 32) + j * 1024);
        __builtin_amdgcn_s_setprio(1);
#pragma unroll
        for (int i = 0; i < 4; ++i)
#pragma unroll
            for (int j = 0; j < 4; ++j)
                acc[i][j] = __builtin_amdgcn_mfma_f32_16x16x32_bf16(
                    a1[i], b1[j], acc[i][j], 0, 0, 0);
        __builtin_amdgcn_s_setprio(0);
        asm volatile("" ::: "memory");
        __builtin_amdgcn_s_barrier();             // BAR2: reads of buf done

        if constexpr (AFP32) {
            if (kt + 1 < T) {
                asm volatile("s_waitcnt vmcnt(0)" ::: "memory"); // A(kt+1),B(kt+1) in
                wrA(kt + 1);
                if (kt + 2 < T) {
                    stageB(kt + 2);
                    asm volatile("" ::: "memory");
                    ldA(kt + 2);
                }
            }
        } else {
            if (kt + 2 < T) { stageA(kt + 2); stageB(kt + 2); }
        }
    }

    // C/D layout: col = lane&15, row = quad*4 + reg  [m89/m91 verified]
    unsigned short* CbW = Cb + (size_t)wr * N + wc;
#pragma unroll
    for (int i = 0; i < 4; ++i)
#pragma unroll
        for (int j = 0; j < 4; ++j)
#pragma unroll
            for (int r = 0; r < 4; ++r)
                CbW[(size_t)(i * 16 + quad * 4 + r) * N + j * 16 + l15] =
                    f2bf(acc[i][j][r]);

    if (Cm) {   // mirrored tile: r-values contiguous -> coalesced ushort4
        unsigned short* CmW = Cm + (size_t)wc * N + wr;
#pragma unroll
        for (int i = 0; i < 4; ++i)
#pragma unroll
            for (int j = 0; j < 4; ++j) {
                ushort4 o;
                o.x = f2bf(acc[i][j][0]);
                o.y = f2bf(acc[i][j][1]);
                o.z = f2bf(acc[i][j][2]);
                o.w = f2bf(acc[i][j][3]);
                *(ushort4*)(CmW + (size_t)(j * 16 + l15) * N + i * 16 + quad * 4) = o;
            }
    }
}

// ---------------------------------------------------------------------------
// Prep: [0,3072)   transpose+cvt x -> xT[b][d][l]
//       [3072,3216) transpose+cvt W -> WT[e][d]
// (main->bf16 dropped: stage2's P-half converts fp32 main in-staging)
// ---------------------------------------------------------------------------
__global__ __launch_bounds__(256) void prep_kernel(
    const float* __restrict__ x, unsigned short* __restrict__ xT,
    const float* __restrict__ W, unsigned short* __restrict__ WT) {
    __shared__ float tile[64][65];
    const int bid = blockIdx.x;
    const int t   = threadIdx.x;
    const float* src;
    unsigned short* dst;
    int ss, dstride;
    if (bid < 3072) {
        const int lb = bid & 15, rest = bid >> 4;
        const int db = rest % 12, b = rest / 12;
        src = x + ((size_t)b * kLX + lb * 64) * kD + db * 64;
        ss  = kD;
        dst = xT + ((size_t)b * kD + db * 64) * kLX + lb * 64;
        dstride = kLX;
    } else {
        const int ti = bid - 3072;
        const int d0 = (ti / 12) * 64, e0 = (ti % 12) * 64;
        src = W + (size_t)d0 * kD + e0;
        ss  = kD;
        dst = WT + (size_t)e0 * kD + d0;
        dstride = kD;
    }
    const int tx = t & 15, ty = t >> 4;
#pragma unroll
    for (int p = 0; p < 4; ++p) {
        int r = p * 16 + ty;
        float4 v = *(const float4*)(src + (size_t)r * ss + tx * 4);
        *(float4*)&tile[r][tx * 4] = v;
    }
    __syncthreads();
#pragma unroll
    for (int p = 0; p < 4; ++p) {
        int dr = p * 16 + ty;
        ushort4 o;
        o.x = f2bf(tile[tx * 4 + 0][dr]);
        o.y = f2bf(tile[tx * 4 + 1][dr]);
        o.z = f2bf(tile[tx * 4 + 2][dr]);
        o.w = f2bf(tile[tx * 4 + 3][dr]);
        *(ushort4*)(dst + (size_t)dr * dstride + tx * 4) = o;
    }
}

// ---------------------------------------------------------------------------
// Stage 2, persistent + per-XCD work-stealing. Grid 512 x 256 thr = exactly
// 2 blocks/CU resident (64 KB LDS). Each block pulls tiles from its XCD's
// private list (ctr[xcd]): per XCD 138 tiles = 42 G (2 batches x 21 triangle,
// LPT: bigger K=1024 tiles first) then 96 P (2 batches x 48, K=768).
// Keeps batch->XCD L2 pinning; removes static-assignment stragglers.
//   G[b] = xT[b] @ xT[b]^T  (triangle, mirror-written)     [bf16 x bf16]
//   P[b] = main[b] @ W      (A fp32 in-staging cvt, B=WT)  [AFP32]
// ---------------------------------------------------------------------------
__global__ __launch_bounds__(256) void gemm_stage2_kernel(
    const unsigned short* __restrict__ xT,
    const float* __restrict__ mainp,
    const unsigned short* __restrict__ WT,
    unsigned short* __restrict__ G, unsigned short* __restrict__ P,
    int* __restrict__ ctr) {
    __shared__ unsigned short As[2][8192];   // 32 KB
    __shared__ unsigned short Bs[2][8192];   // 32 KB
    __shared__ int s_my;
    const int xcd = blockIdx.x & 7;
    for (;;) {
        if (threadIdx.x == 0) s_my = atomicAdd(&ctr[xcd], 1);
        __syncthreads();
        const int my = s_my;
        if (my >= 138) return;               // uniform exit
        if (my < 42) {
            const int bt = my / 21, til = my - bt * 21;
            const int b  = bt * 8 + xcd;
            int bi = (int)((sqrtf(8.f * (float)til + 1.f) - 1.f) * 0.5f);
            if (bi * (bi + 1) / 2 > til) --bi;
            else if ((bi + 1) * (bi + 2) / 2 <= til) ++bi;
            const int bj = til - bi * (bi + 1) / 2;      // bi >= bj
            const unsigned short* base = xT + (size_t)b * kD * kLX;
            unsigned short* Gb = G + (size_t)b * kD * kD;
            gemm_core64<false>(
                base + (size_t)bi * 128 * kLX,
                base + (size_t)bj * 128 * kLX,
                Gb + (size_t)bi * 128 * kD + bj * 128,
                (bi != bj) ? Gb + (size_t)bj * 128 * kD + bi * 128 : nullptr,
                kD, kLX, &As[0][0], &Bs[0][0]);
        } else {
            const int pp = my - 42;
            const int bt = pp / 48, til = pp - bt * 48;
            const int b  = bt * 8 + xcd;
            const int bi = til & 7, bj = til >> 3;       // 8 x 6 tiles
            gemm_core64<true>(
                mainp + (size_t)b * kLM * kD + (size_t)bi * 128 * kD,
                WT + (size_t)bj * 128 * kD,
                P + (size_t)b * kLM * kD + (size_t)bi * 128 * kD + bj * 128,
                nullptr, kD, kD, &As[0][0], &Bs[0][0]);
        }
    }
}

// ---------------------------------------------------------------------------
// Stage 3: A[b] = P[b] @ G[b]  (G symmetric -> NT form with B = G directly)
// 768 blocks of 256 thr (R3-proven).
// ---------------------------------------------------------------------------
__global__ __launch_bounds__(256) void gemm_a_kernel(
    const unsigned short* __restrict__ P, const unsigned short* __restrict__ G,
    unsigned short* __restrict__ Ao) {
    __shared__ unsigned short As[2][8192];
    __shared__ unsigned short Bs[2][8192];
    const int wgid = blockIdx.x;
    const int xcd = wgid & 7, kk = wgid >> 3;           // kk in [0,96)
    const int grp = kk / 48, til = kk - grp * 48;
    const int b   = grp * 8 + xcd;
    const int bi  = til & 7, bj = til >> 3;             // 8 x 6 tiles
    const unsigned short* Ab = P + (size_t)b * kLM * kD + (size_t)bi * 128 * kD;
    const unsigned short* Bb = G + (size_t)b * kD * kD + (size_t)bj * 128 * kD;
    unsigned short* Cb = Ao + (size_t)b * kLM * kD + (size_t)bi * 128 * kD + bj * 128;
    gemm_core64<false>(Ab, Bb, Cb, nullptr, kD, kD, &As[0][0], &Bs[0][0]);
}

// ---------------------------------------------------------------------------
// Fused beta + pooled. Grid (64,16). Wave handles 4 rows.
// Cross-wave LDS pre-reduction -> 1 atomicAdd per (s,lane) per block.
// ---------------------------------------------------------------------------
__global__ __launch_bounds__(256) void pool_kernel(
    const float* __restrict__ mainp, const unsigned short* __restrict__ Aout,
    const float* __restrict__ w, float* __restrict__ out) {
    __shared__ float red[4][24][64];   // 24 KB
    const int b     = blockIdx.y;
    const int chunk = blockIdx.x;           // 64 chunks of 16 rows
    const int t     = threadIdx.x;
    const int wave  = t >> 6, lane = t & 63;
    float w1[12], w2[12], ps[12], pm[12];
#pragma unroll
    for (int s = 0; s < 12; ++s) {
        w1[s] = w[s * 64 + lane];
        w2[s] = w[kD + s * 64 + lane];
        ps[s] = 0.f; pm[s] = 0.f;
    }
#pragma unroll
    for (int rr = 0; rr < 4; ++rr) {
        const int row = chunk * 16 + rr * 4 + wave;
        const float* mr = mainp + ((size_t)b * kLM + row) * kD;
        const unsigned short* ar = Aout + ((size_t)b * kLM + row) * kD;
        float sv[12], mv[12], acc = 0.f;
#pragma unroll
        for (int s = 0; s < 12; ++s) {
            float m_ = mr[s * 64 + lane];
            float a_ = bf2f(ar[s * 64 + lane]);
            sv[s] = m_ - a_;
            mv[s] = m_ * a_;
            acc += sv[s] * w1[s] + mv[s] * w2[s];
        }
#pragma unroll
        for (int off = 32; off; off >>= 1) acc += __shfl_xor(acc, off);
#pragma unroll
        for (int s = 0; s < 12; ++s) { ps[s] += acc * sv[s]; pm[s] += acc * mv[s]; }
    }
#pragma unroll
    for (int s = 0; s < 12; ++s) {
        red[wave][s][lane]      = ps[s];
        red[wave][12 + s][lane] = pm[s];
    }
    __syncthreads();
    float* ob = out + (size_t)b * 2 * kD;
    for (int v = t; v < 24 * 64; v += 256) {
        const int sl = v >> 6, ln = v & 63;
        const float sum = red[0][sl][ln] + red[1][sl][ln] +
                          red[2][sl][ln] + red[3][sl][ln];
        const int d = (sl < 12) ? sl * 64 + ln : kD + (sl - 12) * 64 + ln;
        atomicAdd(&ob[d], sum);
    }
}

extern "C" void kernel_launch(void* const* d_in, const int* in_sizes, int n_in,
                              void* d_out, int out_size, void* d_ws, size_t ws_size,
                              hipStream_t stream) {
    const float* mainp = (const float*)d_in[0];  // (B, LM, D)
    const float* x     = (const float*)d_in[1];  // (B, LX, D)
    const float* W     = (const float*)d_in[2];  // (D, D)
    const float* w     = (const float*)d_in[3];  // (2D, 1)
    float* out = (float*)d_out;                  // (B, 2D)

    char* p = (char*)d_ws;
    unsigned short* xT  = (unsigned short*)p; p += (size_t)kB * kD * kLX * 2;
    unsigned short* G   = (unsigned short*)p; p += (size_t)kB * kD * kD * 2;
    unsigned short* P   = (unsigned short*)p; p += (size_t)kB * kLM * kD * 2;
    unsigned short* Ao  = (unsigned short*)p; p += (size_t)kB * kLM * kD * 2;
    unsigned short* WT  = (unsigned short*)p; p += (size_t)kD * kD * 2;
    int*            ctr = (int*)p;            p += 8 * sizeof(int);

    hipMemsetAsync(out, 0, (size_t)kB * 2 * kD * sizeof(float), stream);
    hipMemsetAsync(ctr, 0, 8 * sizeof(int), stream);

    // x -> xT (transposed bf16), W -> WT (transposed bf16)
    prep_kernel<<<dim3(3216), 256, 0, stream>>>(x, xT, W, WT);

    // G = xT xT^T (triangle+mirror)  ||  P = main @ W   (persistent, stealing)
    gemm_stage2_kernel<<<dim3(512), 256, 0, stream>>>(xT, mainp, WT, G, P, ctr);

    // A = P @ G  (G symmetric)
    gemm_a_kernel<<<dim3(768), 256, 0, stream>>>(P, G, Ao);

    pool_kernel<<<dim3(kLM / 16, kB), 256, 0, stream>>>(mainp, Ao, w, out);
}